// Round 13
// baseline (56.314 us; speedup 1.0000x reference)
//
#include <hip/hip_runtime.h>
#include <math.h>

// N=512, IN_F=128, OUT_F=64, H=4.
// SINGLE-NODE kernel, 256 blocks x 1024 thr (16 waves, 4/SIMD), block = 2 rows.
// c = (alpha@h)@W^T associativity (HW-verified r12). No global sync anywhere.
//   P1 : hts = own-rows ht (VALU row-dots, W streamed) || wa2b[h,k] (bf16)
//   loop 4 chunks of 128 j:
//     C1: stage h chunk -> hcA[j][k] + hcT[k][j] (bf16, conflict-free u32 stores)
//     C2: s2c[h][j] = hcA @ wa2b^T           (MFMA, 8 waves)
//     C3: scores -> exp -> Es bf16 + denom   (all 16 waves, no max-sub)
//     C4: gacc += Es @ hcT                   (MFMA, 16 waves, k-halved)
//   P4 : csh = (g0+g1)@W^T * dinv  ||  psU = hown@U^T   (VALU row-dots)
//   P5 : psV k-split, combine, sigmoid, store.
// MFMA fragment conventions HW-verified in r11/r12:
//   A/B-frag: row = lane&15, k-slice = ks*32+(lane>>4)*8 (8 contig bf16)
//   D: row(m) = (lane>>4)*4+q, col(n) = lane&15.

typedef short short8 __attribute__((ext_vector_type(8)));
typedef float f32x4 __attribute__((ext_vector_type(4)));
union CDu { f32x4 v; float f[4]; };

#define MFMA(A,B,C) __builtin_amdgcn_mfma_f32_16x16x32_bf16((A),(B),(C),0,0,0)

__device__ __forceinline__ unsigned pk2(float lo, float hi) {
    return __builtin_amdgcn_perm(__float_as_uint(hi) + 0x8000u,
                                 __float_as_uint(lo) + 0x8000u, 0x07060302u);
}
__device__ __forceinline__ ushort bf1(float x) {
    return (ushort)((__float_as_uint(x) + 0x8000u) >> 16);
}
__device__ __forceinline__ float wsum(float v) {
    #pragma unroll
    for (int o = 32; o; o >>= 1) v += __shfl_xor(v, o, 64);
    return v;
}

__global__ __launch_bounds__(1024) void k_mono(
    const float* __restrict__ h, const int* __restrict__ adj,
    const float* __restrict__ ew, const float* __restrict__ W,
    const float* __restrict__ a, const float* __restrict__ U,
    const float* __restrict__ V, float* __restrict__ out)
{
    __shared__ float ash[512];                    // a[4][128]
    __shared__ float hown[256];                   // own 2 h rows f32
    __shared__ float hts[512];                    // own 2 ht rows f32
    __shared__ float s1s[32];                     // [r][g*4+h]
    __shared__ float dacc[16], dinv[8];
    __shared__ __align__(16) char wa2b[16 * 272]; // bf16 [h pad16][136]
    __shared__ __align__(16) char hcA[128 * 272]; // bf16 [j][136]
    __shared__ __align__(16) char hcT[128 * 272]; // bf16 [k][136] (j transposed)
    __shared__ __align__(16) char Esb[16 * 272];  // bf16 [rh pad16][136]
    __shared__ float s2c[4 * 132];                // [h][j]
    __shared__ float gs2[2 * 8 * 128];            // [khalf][rh][k]
    __shared__ float csh[512], psU[512], psV[1024];

    const int t = threadIdx.x, l = t & 63, w = t >> 6;
    const int i0 = blockIdx.x * 2;

    // ---------------- P0 ----------------
    if (t < 128)      ((float4*)ash)[t]        = ((const float4*)a)[t];
    else if (t < 192) ((float4*)hown)[t - 128] = ((const float4*)(h + i0 * 128))[t - 128];
    if (t < 16) dacc[t] = 0.f;
    {   // zero Esb + wa2b (rows >=8 / >=4 must stay zero)
        unsigned* E4 = (unsigned*)Esb; unsigned* W4 = (unsigned*)wa2b;
        E4[t] = 0u; W4[t] = 0u;
        if (t < 64) { E4[1024 + t] = 0u; W4[1024 + t] = 0u; }
    }
    __syncthreads();

    // ---------------- P1: own ht || wa2 ----------------
    if (t < 512) {
        const int r = t >> 8, m = t & 255;
        const float4* Wv = (const float4*)(W + m * 128);
        const float* hp = hown + r * 128;
        float acc = 0.f;
        #pragma unroll
        for (int kk = 0; kk < 32; ++kk) {
            float4 w4 = Wv[kk];
            acc += w4.x*hp[kk*4] + w4.y*hp[kk*4+1] + w4.z*hp[kk*4+2] + w4.w*hp[kk*4+3];
        }
        hts[r * 256 + m] = acc;
    } else {
        const int idx = t - 512, h2 = idx >> 7, k = idx & 127;
        float acc = 0.f;
        #pragma unroll 8
        for (int f = 0; f < 64; ++f)
            acc += W[(h2 * 64 + f) * 128 + k] * ash[h2 * 128 + 64 + f];
        *(ushort*)(wa2b + h2 * 272 + k * 2) = bf1(acc);
    }

    f32x4 gacc = {0.f, 0.f, 0.f, 0.f};
    int adv; float ewv;

    // ---------------- chunk loop: 4 x 128 j ----------------
    for (int c = 0; c < 4; ++c) {
        const int jg = c * 128;
        __syncthreads();   // prev C4 done -> hcA/hcT free; P1/s1 visible

        {   // C1: stage. thread = (j-pair jp = t&63, k-block kb = t>>6)
            const int j0 = (t & 63) * 2, k8 = (t >> 6) * 8;
            const float* hp0 = h + (jg + j0) * 128 + k8;
            float4 a0 = *(const float4*)hp0, a1 = *(const float4*)(hp0 + 4);
            float4 b0 = *(const float4*)(hp0 + 128), b1 = *(const float4*)(hp0 + 132);
            // hcT rows k8..k8+7, col j0 (u32 = {row j0, row j0+1}); lanes -> +1 dword: conflict-free
            unsigned va[8] = { pk2(a0.x,b0.x), pk2(a0.y,b0.y), pk2(a0.z,b0.z), pk2(a0.w,b0.w),
                               pk2(a1.x,b1.x), pk2(a1.y,b1.y), pk2(a1.z,b1.z), pk2(a1.w,b1.w) };
            #pragma unroll
            for (int q = 0; q < 8; ++q)
                *(unsigned*)(hcT + (k8 + q) * 272 + j0 * 2) = va[q];
            // hcA rows j0, j0+1 (uint4)
            *(uint4*)(hcA + j0 * 272 + k8 * 2) =
                make_uint4(pk2(a0.x,a0.y), pk2(a0.z,a0.w), pk2(a1.x,a1.y), pk2(a1.z,a1.w));
            *(uint4*)(hcA + (j0 + 1) * 272 + k8 * 2) =
                make_uint4(pk2(b0.x,b0.y), pk2(b0.z,b0.w), pk2(b1.x,b1.y), pk2(b1.z,b1.w));
        }
        {   // adj/ew prefetch with C3's mapping
            const int rh = t >> 7, jl = t & 127, r = rh >> 2;
            adv = adj[(i0 + r) * 512 + jg + jl];
            ewv = ew [(i0 + r) * 512 + jg + jl];
        }
        if (c == 0 && t < 32) {   // s1 from own ht rows
            const int r = t >> 4, gh = t & 15, g = gh >> 2, hh = gh & 3;
            float s = 0.f;
            #pragma unroll 8
            for (int f = 0; f < 64; ++f)
                s += hts[r * 256 + g * 64 + f] * ash[hh * 128 + f];
            s1s[t] = s;
        }
        __syncthreads();

        if (w < 8) {   // C2: s2 = hcA @ wa2b^T (MFMA), m-tile = w
            f32x4 cs = {0.f, 0.f, 0.f, 0.f};
            #pragma unroll
            for (int ks = 0; ks < 4; ++ks) {
                const int kb = ks * 32 + (l >> 4) * 8;
                short8 Af = *(const short8*)(hcA + (w * 16 + (l & 15)) * 272 + kb * 2);
                short8 Bf = *(const short8*)(wa2b + (l & 15) * 272 + kb * 2);
                cs = MFMA(Af, Bf, cs);
            }
            if ((l & 15) < 4) {   // D: row = j-in-tile, col = h
                CDu cd; cd.v = cs;
                #pragma unroll
                for (int q = 0; q < 4; ++q)
                    s2c[(l & 15) * 132 + w * 16 + (l >> 4) * 4 + q] = cd.f[q];
            }
        }
        __syncthreads();

        {   // C3: scores + exp + denom (all 16 waves)
            const int rh = t >> 7, jl = t & 127, r = rh >> 2, hh = rh & 3;
            float e = s1s[r * 16 + c * 4 + hh] + s2c[hh * 132 + jl];
            e = (e >= 0.f) ? e : 0.2f * e;
            e = (adv > 0) ? e * ewv : -9.0e15f;
            float x = __expf(e);   // masked -> exactly 0
            *(ushort*)(Esb + rh * 272 + jl * 2) = bf1(x);
            float s = wsum(x);
            if (l == 0) dacc[w] += s;   // wave w <-> (rh, jl-half), fixed
        }
        __syncthreads();

        {   // C4: g += Es @ hcT (MFMA); wave = (n-tile = w&7, k-half = w>>3)
            const int nt = w & 7, kh = w >> 3;
            #pragma unroll
            for (int ki = 0; ki < 2; ++ki) {
                const int kb = (kh * 2 + ki) * 32 + (l >> 4) * 8;
                short8 Af = *(const short8*)(Esb + (l & 15) * 272 + kb * 2);
                short8 Bf = *(const short8*)(hcT + (nt * 16 + (l & 15)) * 272 + kb * 2);
                gacc = MFMA(Af, Bf, gacc);
            }
        }
    }
    __syncthreads();

    // ---------------- P3: spill g, denominators ----------------
    {
        CDu cd; cd.v = gacc;
        const int nt = w & 7, kh = w >> 3;
        #pragma unroll
        for (int q = 0; q < 4; ++q) {
            int rh = (l >> 4) * 4 + q;
            if (rh < 8)
                gs2[kh * 1024 + rh * 128 + nt * 16 + (l & 15)] = cd.f[q];
        }
    }
    if (t < 8) dinv[t] = 1.f / (dacc[2 * t] + dacc[2 * t + 1]);
    __syncthreads();

    // ---------------- P4: c = g@W^T * dinv  ||  psU = hown@U^T ----------------
    if (t < 512) {
        const int r = t >> 8, m = t & 255, rh = r * 4 + (m >> 6);
        const float4* Wv = (const float4*)(W + m * 128);
        const float* g0 = gs2 + rh * 128;
        const float* g1 = gs2 + 1024 + rh * 128;
        float acc = 0.f;
        #pragma unroll
        for (int kk = 0; kk < 32; ++kk) {
            float4 w4 = Wv[kk];
            acc += w4.x*(g0[kk*4]  +g1[kk*4])   + w4.y*(g0[kk*4+1]+g1[kk*4+1])
                 + w4.z*(g0[kk*4+2]+g1[kk*4+2]) + w4.w*(g0[kk*4+3]+g1[kk*4+3]);
        }
        csh[r * 256 + m] = acc * dinv[rh];
    } else {
        const int i2 = t - 512, r = i2 >> 8, m = i2 & 255;
        const float4* Uv = (const float4*)(U + m * 128);
        const float* hp = hown + r * 128;
        float acc = 0.f;
        #pragma unroll
        for (int kk = 0; kk < 32; ++kk) {
            float4 u4 = Uv[kk];
            acc += u4.x*hp[kk*4] + u4.y*hp[kk*4+1] + u4.z*hp[kk*4+2] + u4.w*hp[kk*4+3];
        }
        psU[r * 256 + m] = acc;
    }
    __syncthreads();

    // ---------------- P5: V-part (k-split), combine, sigmoid ----------------
    {
        const int half = t >> 9, r = (t >> 8) & 1, m = t & 255;
        const float4* Vv = (const float4*)(V + m * 256 + half * 128);
        const float* cp = csh + r * 256 + half * 128;
        float acc = 0.f;
        #pragma unroll
        for (int kk = 0; kk < 32; ++kk) {
            float4 v4 = Vv[kk];
            acc += v4.x*cp[kk*4] + v4.y*cp[kk*4+1] + v4.z*cp[kk*4+2] + v4.w*cp[kk*4+3];
        }
        psV[(half * 2 + r) * 256 + m] = acc;
    }
    __syncthreads();
    if (t < 512) {
        const int r = t >> 8, m = t & 255;
        float x = psU[r * 256 + m] + psV[r * 256 + m] + psV[(2 + r) * 256 + m];
        out[(i0 + r) * 256 + m] = 1.f / (1.f + __expf(-x));
    }
}

extern "C" void kernel_launch(void* const* d_in, const int* in_sizes, int n_in,
                              void* d_out, int out_size, void* d_ws, size_t ws_size,
                              hipStream_t stream) {
    const float* h   = (const float*)d_in[0];
    const int*   adj = (const int*)d_in[1];
    const float* ew  = (const float*)d_in[2];
    const float* W   = (const float*)d_in[3];
    const float* a   = (const float*)d_in[4];
    const float* U   = (const float*)d_in[5];
    const float* V   = (const float*)d_in[6];
    float* out = (float*)d_out;

    k_mono<<<256, 1024, 0, stream>>>(h, adj, ew, W, a, U, V, out);
}

// Round 14
// 24.608 us; speedup vs baseline: 2.2885x; 2.2885x over previous
//
#include <hip/hip_runtime.h>
#include <math.h>

// N=512, IN_F=128, OUT_F=64, H=4.
// 3-node pipeline, latency-optimized content:
//  K1 (288 blk x 256): ht rows 2b,2b+1 -> htbT[f][j] bf16 j-pair + s1 + s2;
//                      tail blocks pack U,V -> bf16.
//  K2 (256 blk = 64 i-tiles x 4 j-chunks, 512 thr): scores+exp (no max-sub,
//      masked -> exp(-9e15) = 0 exactly), Es bf16 (rh = h*8+r), denominators
//      via 16-lane shfl, num = Es @ htT via MFMA -> partial num/den per chunk.
//  K3 (256 blk x 512): c = (sum_q num)/(sum_q den), bf16 U/V epilogue, sigmoid.
// MFMA fragment layout HW-verified r11/r12: A/B row = lane&15, k-slice =
// ks*32+(lane>>4)*8 (8 contig bf16); D row = (lane>>4)*4+q, col = lane&15.

typedef short short8 __attribute__((ext_vector_type(8)));
typedef float f32x4 __attribute__((ext_vector_type(4)));
union CDu { f32x4 v; float f[4]; };

#define MFMA(A,B,C) __builtin_amdgcn_mfma_f32_16x16x32_bf16((A),(B),(C),0,0,0)

__device__ __forceinline__ unsigned pk2(float lo, float hi) {
    return __builtin_amdgcn_perm(__float_as_uint(hi) + 0x8000u,
                                 __float_as_uint(lo) + 0x8000u, 0x07060302u);
}
__device__ __forceinline__ float asf(unsigned u) { return __uint_as_float(u); }

// ---------------- K1 ----------------
__global__ __launch_bounds__(256) void k1(
    const float* __restrict__ h, const float* __restrict__ W,
    const float* __restrict__ a, const float* __restrict__ U,
    const float* __restrict__ V,
    ushort* __restrict__ htbT, float* __restrict__ s1, float* __restrict__ s2p,
    unsigned* __restrict__ Ub, unsigned* __restrict__ Vb)
{
    const int t = threadIdx.x;
    if (blockIdx.x >= 256) {   // weight packing tail
        const int m = (blockIdx.x - 256) * 256 + t;
        const float2* U2 = (const float2*)U;
        const float2* V2 = (const float2*)V;
        #pragma unroll
        for (int k = 0; k < 2; ++k) {
            float2 f = U2[m + k * 8192];
            Ub[m + k * 8192] = pk2(f.x, f.y);
        }
        #pragma unroll
        for (int k = 0; k < 4; ++k) {
            float2 f = V2[m + k * 8192];
            Vb[m + k * 8192] = pk2(f.x, f.y);
        }
        return;
    }
    __shared__ float hsh[2 * 128];
    __shared__ float ash[512];
    __shared__ float hts[2 * 256];
    const int i0 = blockIdx.x * 2;
    if (t < 64)       ((float4*)hsh)[t]      = ((const float4*)(h + i0 * 128))[t];
    else if (t < 192) ((float4*)ash)[t - 64] = ((const float4*)a)[t - 64];
    __syncthreads();

    float acc0 = 0.f, acc1 = 0.f;
    const float4* Wv = (const float4*)(W + t * 128);
    #pragma unroll
    for (int kk = 0; kk < 32; ++kk) {
        float4 w4 = Wv[kk];
        const float* h0 = hsh + kk * 4;
        const float* h1 = hsh + 128 + kk * 4;
        acc0 += w4.x * h0[0] + w4.y * h0[1] + w4.z * h0[2] + w4.w * h0[3];
        acc1 += w4.x * h1[0] + w4.y * h1[1] + w4.z * h1[2] + w4.w * h1[3];
    }
    // transposed bf16 store: htbT[feature t][j-pair i0/2]
    *(unsigned*)((char*)htbT + t * 1024 + i0 * 2) = pk2(acc0, acc1);
    hts[t]       = acc0;
    hts[256 + t] = acc1;
    __syncthreads();

    if (t < 40) {
        const int rr = t & 1, o = t >> 1;
        const float* x;
        const float* y;
        if (o < 16) { x = hts + rr * 256 + (o >> 2) * 64;  y = ash + (o & 3) * 128; }
        else        { x = hts + rr * 256 + (o - 16) * 64;  y = ash + (o - 16) * 128 + 64; }
        float s = 0.f;
        #pragma unroll
        for (int ff = 0; ff < 64; ++ff) {
            int f = (ff + (t << 3)) & 63;
            s += x[f] * y[f];
        }
        if (o < 16) s1[(i0 + rr) * 16 + (o >> 2) * 4 + (o & 3)] = s;
        else        s2p[(o - 16) * 512 + i0 + rr] = s;
    }
}

// ---------------- K2: partial attention x aggregate ----------------
__global__ __launch_bounds__(512) void k2(
    const int* __restrict__ adj, const float* __restrict__ ew,
    const ushort* __restrict__ htbT, const float* __restrict__ s1,
    const float* __restrict__ s2p,
    float* __restrict__ nump, float* __restrict__ denp)
{
    __shared__ __align__(16) char hTl[256 * 272];  // bf16 [f][j-chunk], 272B pitch
    __shared__ __align__(16) char Es[32 * 272];    // bf16 [rh = h*8+r][j]
    __shared__ float s2sh[512];                    // [h][128]
    __shared__ float s1sh[128];                    // [r][16]
    const int t = threadIdx.x, l = t & 63, w = t >> 6;
    const int it = blockIdx.x >> 2, q = blockIdx.x & 3;
    const int i0 = it * 8, jg = q * 128;

    #pragma unroll
    for (int p = 0; p < 8; ++p) {   // stage htbT chunk, coalesced uint4
        int lin = p * 512 + t, row = lin >> 4, jseg = (lin & 15) * 8;
        uint4 v = *(const uint4*)(htbT + row * 512 + jg + jseg);
        *(uint4*)(hTl + row * 272 + jseg * 2) = v;
    }
    s2sh[t] = s2p[(t >> 7) * 512 + jg + (t & 127)];
    if (t < 128) s1sh[t] = s1[(i0 + (t >> 4)) * 16 + (t & 15)];
    __syncthreads();

    {   // scores + exp -> Es; thread = (rh = t>>4, 8 consecutive j)
        const int rh = t >> 4, j8 = (t & 15) * 8;
        const int r = rh & 7, hh = rh >> 3;
        const float s1v = s1sh[r * 16 + q * 4 + hh];
        const int base = (i0 + r) * 512 + jg + j8;
        int4   a0 = *(const int4*)(adj + base), a1 = *(const int4*)(adj + base + 4);
        float4 w0 = *(const float4*)(ew + base), w1 = *(const float4*)(ew + base + 4);
        float v[8];
        const float* sp = s2sh + hh * 128 + j8;
        int   ai[8] = {a0.x,a0.y,a0.z,a0.w,a1.x,a1.y,a1.z,a1.w};
        float wi[8] = {w0.x,w0.y,w0.z,w0.w,w1.x,w1.y,w1.z,w1.w};
        float den = 0.f;
        #pragma unroll
        for (int k = 0; k < 8; ++k) {
            float e = s1v + sp[k];
            e = (e >= 0.f) ? e : 0.2f * e;
            e = (ai[k] > 0) ? e * wi[k] : -9.0e15f;
            v[k] = __expf(e);           // masked -> exactly 0
            den += v[k];
        }
        *(uint4*)(Es + rh * 272 + j8 * 2) =
            make_uint4(pk2(v[0],v[1]), pk2(v[2],v[3]), pk2(v[4],v[5]), pk2(v[6],v[7]));
        #pragma unroll
        for (int o = 1; o < 16; o <<= 1) den += __shfl_xor(den, o, 64);
        if ((l & 15) == 0) denp[(q * 64 + it) * 32 + rh] = den;
    }
    __syncthreads();

    {   // num = Es @ hTl^T slices; wave w -> pairs p = 2w, 2w+1
        #pragma unroll
        for (int pp = 0; pp < 2; ++pp) {
            const int p = w * 2 + pp, mt = p >> 3, ntl = p & 7;
            const int nt = mt * 8 + ntl;
            f32x4 acc = {0.f, 0.f, 0.f, 0.f};
            #pragma unroll
            for (int ks = 0; ks < 4; ++ks) {
                const int kb = ks * 32 + (l >> 4) * 8;
                short8 Af = *(const short8*)(Es + (mt * 16 + (l & 15)) * 272 + kb * 2);
                short8 Bf = *(const short8*)(hTl + (nt * 16 + (l & 15)) * 272 + kb * 2);
                acc = MFMA(Af, Bf, acc);
            }
            CDu cd; cd.v = acc;
            const int fcol = ntl * 16 + (l & 15);   // f within mt's 128-block
            const int fh = fcol >> 6;
            #pragma unroll
            for (int q4 = 0; q4 < 4; ++q4) {
                const int rloc = (l >> 4) * 4 + q4;
                if ((rloc >> 3) == fh) {            // head-matching quadrant
                    const int rh = mt * 16 + rloc;
                    nump[((q * 64 + it) * 32 + rh) * 64 + (fcol & 63)] = cd.f[q4];
                }
            }
        }
    }
}

// ---------------- K3: combine + epilogue ----------------
__global__ __launch_bounds__(512) void k3(
    const float* __restrict__ h, const float* __restrict__ nump,
    const float* __restrict__ denp, const unsigned* __restrict__ Ub,
    const unsigned* __restrict__ Vb, float* __restrict__ out)
{
    __shared__ float hsh[2 * 128];
    __shared__ float csh[2 * 256];
    __shared__ float psum[4 * 256];
    const int t = threadIdx.x;
    const int i0 = blockIdx.x * 2;
    const int it = i0 >> 3, rbase = i0 & 7;

    if (t < 64) ((float4*)hsh)[t] = ((const float4*)(h + i0 * 128))[t];
    {   // c = (sum_q num) / (sum_q den)
        const int r = t >> 8, hf = t & 255, hh = hf >> 6, fp = hf & 63;
        const int rh = hh * 8 + rbase + r;
        float num = 0.f, den = 0.f;
        #pragma unroll
        for (int qq = 0; qq < 4; ++qq) {
            num += nump[((qq * 64 + it) * 32 + rh) * 64 + fp];
            den += denp[(qq * 64 + it) * 32 + rh];
        }
        csh[r * 256 + hf] = num / den;
    }
    __syncthreads();

    {   // bf16 epilogue, K-half split
        const int half = t >> 8, col = t & 255;
        float acc0 = 0.f, acc1 = 0.f;
        const uint4* Up = (const uint4*)(Ub + col * 64 + half * 32);
        #pragma unroll
        for (int b4 = 0; b4 < 8; ++b4) {
            uint4 uv = Up[b4];
            unsigned ua[4] = {uv.x, uv.y, uv.z, uv.w};
            #pragma unroll
            for (int e = 0; e < 4; ++e) {
                const int k = half * 64 + b4 * 8 + e * 2;
                float ulo = asf(ua[e] << 16), uhi = asf(ua[e] & 0xffff0000u);
                acc0 += ulo * hsh[k]       + uhi * hsh[k + 1];
                acc1 += ulo * hsh[128 + k] + uhi * hsh[128 + k + 1];
            }
        }
        const uint4* Vp = (const uint4*)(Vb + col * 128 + half * 64);
        #pragma unroll
        for (int b4 = 0; b4 < 16; ++b4) {
            uint4 vv = Vp[b4];
            unsigned va[4] = {vv.x, vv.y, vv.z, vv.w};
            #pragma unroll
            for (int e = 0; e < 4; ++e) {
                const int k = half * 128 + b4 * 8 + e * 2;
                float vlo = asf(va[e] << 16), vhi = asf(va[e] & 0xffff0000u);
                acc0 += vlo * csh[k]       + vhi * csh[k + 1];
                acc1 += vlo * csh[256 + k] + vhi * csh[256 + k + 1];
            }
        }
        psum[(half * 2 + 0) * 256 + col] = acc0;
        psum[(half * 2 + 1) * 256 + col] = acc1;
    }
    __syncthreads();
    {
        const int r = t >> 8, col = t & 255;
        float x = psum[r * 256 + col] + psum[(2 + r) * 256 + col];
        out[(i0 + r) * 256 + col] = 1.f / (1.f + __expf(-x));
    }
}

extern "C" void kernel_launch(void* const* d_in, const int* in_sizes, int n_in,
                              void* d_out, int out_size, void* d_ws, size_t ws_size,
                              hipStream_t stream) {
    const float* h   = (const float*)d_in[0];
    const int*   adj = (const int*)d_in[1];
    const float* ew  = (const float*)d_in[2];
    const float* W   = (const float*)d_in[3];
    const float* a   = (const float*)d_in[4];
    const float* U   = (const float*)d_in[5];
    const float* V   = (const float*)d_in[6];
    float* out = (float*)d_out;

    ushort*  htbT = (ushort*)d_ws;                 // 256*512 bf16 = 256 KB
    float*   s1   = (float*)(htbT + 256 * 512);    // 512*16
    float*   s2p  = s1 + 512 * 16;                 // 4*512
    unsigned* Ub  = (unsigned*)(s2p + 2048);       // 16384 u32
    unsigned* Vb  = Ub + 16384;                    // 32768 u32
    float*   nump = (float*)(Vb + 32768);          // 4*64*32*64 f32 = 2 MB
    float*   denp = nump + 4 * 64 * 32 * 64;       // 4*64*32 f32

    k1<<<288, 256, 0, stream>>>(h, W, a, U, V, htbT, s1, s2p, Ub, Vb);
    k2<<<256, 512, 0, stream>>>(adj, ew, htbT, s1, s2p, nump, denp);
    k3<<<256, 512, 0, stream>>>(h, nump, denp, Ub, Vb, out);
}